// Round 1
// baseline (186.628 us; speedup 1.0000x reference)
//
#include <hip/hip_runtime.h>

// ---------------------------------------------------------------------------
// Attention fused kernel for MI355X (gfx950)
//   x:[4,4096,1024] f32, Wq/Wk/Wv:[128,1024] f32 -> out:[4,4096,128] f32
//   out = softmax(causal(Q K^T / sqrt(128))) V,  Q/K/V = x @ W^T
// Strategy: bf16 MFMA (16x16x32) for projections and attention.
//   ws layout: [0,4M) q_bf16 (pre-scaled by log2e/sqrt(128)), [4M,8M) k_bf16,
//              [8M,12M) v^T bf16 [B][128][T], [12M, ..) W bf16 [384][1024]
// ---------------------------------------------------------------------------

typedef __attribute__((ext_vector_type(8))) short short8;
typedef __attribute__((ext_vector_type(8))) unsigned short ushort8;
typedef __attribute__((ext_vector_type(4))) float f32x4;
typedef unsigned int u32;
typedef unsigned short u16;

#define MFMA_BF16(a, b, c) __builtin_amdgcn_mfma_f32_16x16x32_bf16((a), (b), (c), 0, 0, 0)

__device__ __forceinline__ void gload16(const void* g, void* l) {
  // async global->LDS, 16B per lane; LDS dest is wave-uniform base + lane*16
  __builtin_amdgcn_global_load_lds((const __attribute__((address_space(1))) u32*)g,
                                   (__attribute__((address_space(3))) u32*)l, 16, 0, 0);
}

__device__ __forceinline__ u16 f2bf(float f) {  // f32 -> bf16 bits, RNE
  u32 u = __builtin_bit_cast(u32, f);
  u = u + 0x7FFFu + ((u >> 16) & 1u);
  return (u16)(u >> 16);
}

__device__ __forceinline__ short8 cvt8(const float* p) {  // 8 f32 -> bf16x8 frag
  float4 a = *(const float4*)p;
  float4 b = *(const float4*)(p + 4);
  short8 v;
  v[0] = (short)f2bf(a.x); v[1] = (short)f2bf(a.y);
  v[2] = (short)f2bf(a.z); v[3] = (short)f2bf(a.w);
  v[4] = (short)f2bf(b.x); v[5] = (short)f2bf(b.y);
  v[6] = (short)f2bf(b.z); v[7] = (short)f2bf(b.w);
  return v;
}

// ---------------- kernel 0: W f32 -> bf16 (Wb[384][1024]) -------------------
__global__ __launch_bounds__(256) void wconv_kernel(const float* __restrict__ Wq,
                                                    const float* __restrict__ Wk,
                                                    const float* __restrict__ Wv,
                                                    u16* __restrict__ Wb) {
  int g = (blockIdx.x * 256 + threadIdx.x) * 8;  // 393216 elems total
  const float* src;
  if (g < 131072)      src = Wq + g;
  else if (g < 262144) src = Wk + (g - 131072);
  else                 src = Wv + (g - 262144);
  float4 a = *(const float4*)src;
  float4 b = *(const float4*)(src + 4);
  ushort8 o;
  o[0] = f2bf(a.x); o[1] = f2bf(a.y); o[2] = f2bf(a.z); o[3] = f2bf(a.w);
  o[4] = f2bf(b.x); o[5] = f2bf(b.y); o[6] = f2bf(b.z); o[7] = f2bf(b.w);
  *(ushort8*)(Wb + g) = o;
}

// ---------------- kernel 1: fused QKV projection ----------------------------
// Block: 256 thr (4 waves x 16 rows) -> 64-row M tile; K staged 64 at a time.
// Wlds: [384 rows][64 bf16] linear, 16B-chunk XOR swizzle (chunk ^= row&7).
#define QK_SCALE 0.127517446f  // (1/sqrt(128)) * log2(e): softmax in exp2 domain

__global__ __launch_bounds__(256) void qkv_proj_kernel(const float* __restrict__ x,
                                                       const u16* __restrict__ Wb,
                                                       u16* __restrict__ qout,
                                                       u16* __restrict__ kout,
                                                       u16* __restrict__ vtout) {
  __shared__ __align__(16) unsigned char Wlds[49152];  // 384*64*2
  const int tid = threadIdx.x;
  const int w = tid >> 6;
  const int l = tid & 63;
  const int lg = l >> 4, ll = l & 15;
  const int m0 = blockIdx.x * 64;

  f32x4 acc[24];
#pragma unroll
  for (int t = 0; t < 24; ++t) acc[t] = f32x4{0.f, 0.f, 0.f, 0.f};

  const float* xr = x + (size_t)(m0 + w * 16 + ll) * 1024 + lg * 8;

  for (int k0 = 0; k0 < 1024; k0 += 64) {
    __syncthreads();  // protect Wlds from previous iteration's readers
#pragma unroll
    for (int c = 0; c < 12; ++c) {  // 3072 16B chunks
      int L = c * 256 + tid;
      int row = L >> 3, chp = L & 7;
      int gch = chp ^ (row & 7);  // pre-swizzled global source (rule #21)
      gload16((const char*)Wb + row * 2048 + k0 * 2 + gch * 16,
              Wlds + c * 4096 + w * 1024);
    }
    __syncthreads();  // drains vmcnt
    short8 a0 = cvt8(xr + k0);
    short8 a1 = cvt8(xr + k0 + 32);
#pragma unroll
    for (int t = 0; t < 24; ++t) {
      int row = t * 16 + ll;
      const char* base = (const char*)Wlds + row * 128;
      int sw = (row & 7) << 4;
      acc[t] = MFMA_BF16(a0, *(const short8*)(base + ((lg * 16) ^ sw)), acc[t]);
      acc[t] = MFMA_BF16(a1, *(const short8*)(base + ((64 + lg * 16) ^ sw)), acc[t]);
    }
  }

  const int rbase = m0 + w * 16 + lg * 4;
#pragma unroll
  for (int t = 0; t < 8; ++t)
#pragma unroll
    for (int r = 0; r < 4; ++r)
      qout[(size_t)(rbase + r) * 128 + t * 16 + ll] = f2bf(acc[t][r] * QK_SCALE);
#pragma unroll
  for (int t = 0; t < 8; ++t)
#pragma unroll
    for (int r = 0; r < 4; ++r)
      kout[(size_t)(rbase + r) * 128 + t * 16 + ll] = f2bf(acc[8 + t][r]);
#pragma unroll
  for (int t = 0; t < 8; ++t)
#pragma unroll
    for (int r = 0; r < 4; ++r) {
      int row = rbase + r;
      int d = t * 16 + ll;
      vtout[(size_t)((row >> 12) * 128 + d) * 4096 + (row & 4095)] = f2bf(acc[16 + t][r]);
    }
}

// ---------------- kernel 2: causal flash attention --------------------------
// Grid 512 = 4 batches x 128 q-tiles (32 rows), longest tiles dispatched first.
// Block 128 thr = 2 waves x 16 rows. KVBLK=64. K/Vt LDS tiles XOR-swizzled.
#define NEG_INF (-1e30f)

__global__ __launch_bounds__(128) void attn_kernel(const u16* __restrict__ qws,
                                                   const u16* __restrict__ kws,
                                                   const u16* __restrict__ vtws,
                                                   float* __restrict__ out) {
  __shared__ __align__(16) unsigned char Klds[16384];  // [64 kv][128 d] bf16 swz
  __shared__ __align__(16) unsigned char Vlds[16384];  // [128 d][64 kv] bf16 swz
  __shared__ __align__(16) u16 Plds[2][1152];          // per wave [16][72] bf16

  const int tid = threadIdx.x;
  const int w = tid >> 6;
  const int l = tid & 63;
  const int lg = l >> 4, ll = l & 15;
  const int bi = (int)(blockIdx.x & 3);
  const int qt = 127 - (int)(blockIdx.x >> 2);  // reversed: long blocks first
  const int q0 = qt * 32 + w * 16;              // this wave's first q row

  // Q fragments (already scaled by log2e/sqrt(128)), kept in registers
  short8 qa[4];
  const u16* qbase = qws + (size_t)(bi * 4096 + q0 + ll) * 128 + lg * 8;
#pragma unroll
  for (int kc = 0; kc < 4; ++kc) qa[kc] = *(const short8*)(qbase + kc * 32);

  f32x4 o[8];
#pragma unroll
  for (int n = 0; n < 8; ++n) o[n] = f32x4{0.f, 0.f, 0.f, 0.f};
  float m[4] = {NEG_INF, NEG_INF, NEG_INF, NEG_INF};
  float lsum[4] = {0.f, 0.f, 0.f, 0.f};

  const char* kbatch = (const char*)kws + (size_t)bi * 4096 * 256;
  const char* vbatch = (const char*)vtws + (size_t)bi * 128 * 8192;
  const int nsteps = (qt >> 1) + 1;

  for (int s = 0; s < nsteps; ++s) {
    const int kv0 = s * 64;
    __syncthreads();  // previous iteration's consumers done
#pragma unroll
    for (int c = 0; c < 8; ++c) {  // K tile: 1024 chunks
      int L = c * 128 + tid;
      int row = L >> 4, chp = L & 15;
      int gch = chp ^ (row & 7);
      gload16(kbatch + (size_t)(kv0 + row) * 256 + gch * 16, Klds + c * 2048 + w * 1024);
    }
#pragma unroll
    for (int c = 0; c < 8; ++c) {  // Vt tile: 1024 chunks
      int L = c * 128 + tid;
      int row = L >> 3, chp = L & 7;
      int gch = chp ^ (row & 7);
      gload16(vbatch + (size_t)row * 8192 + kv0 * 2 + gch * 16, Vlds + c * 2048 + w * 1024);
    }
    __syncthreads();  // drains vmcnt (compiler emits vmcnt(0) before s_barrier)

    // S = Q K^T  (S[i][j]: i = lg*4+r, j = kv0 + n*16 + ll)
    f32x4 sacc[4];
#pragma unroll
    for (int n = 0; n < 4; ++n) sacc[n] = f32x4{0.f, 0.f, 0.f, 0.f};
#pragma unroll
    for (int n = 0; n < 4; ++n) {
      int rowb = n * 16 + ll;
      const char* kr = (const char*)Klds + rowb * 256;
      int sw = (rowb & 7) << 4;
#pragma unroll
      for (int kc = 0; kc < 4; ++kc) {
        short8 kb = *(const short8*)(kr + ((kc * 64 + lg * 16) ^ sw));
        sacc[n] = MFMA_BF16(qa[kc], kb, sacc[n]);
      }
    }
    // causal mask (only near the diagonal; wave-uniform branch)
    if (kv0 + 63 > q0) {
#pragma unroll
      for (int n = 0; n < 4; ++n)
#pragma unroll
        for (int r = 0; r < 4; ++r)
          if (kv0 + n * 16 + ll > q0 + lg * 4 + r) sacc[n][r] = NEG_INF;
    }
    // online softmax (exp2 domain; scale folded into Q)
#pragma unroll
    for (int r = 0; r < 4; ++r) {
      float mx = fmaxf(fmaxf(sacc[0][r], sacc[1][r]), fmaxf(sacc[2][r], sacc[3][r]));
#pragma unroll
      for (int d = 1; d < 16; d <<= 1) mx = fmaxf(mx, __shfl_xor(mx, d));
      float mn = fmaxf(m[r], mx);
      float alpha = exp2f(m[r] - mn);
      m[r] = mn;
      float rs = 0.f;
#pragma unroll
      for (int n = 0; n < 4; ++n) {
        float p = exp2f(sacc[n][r] - mn);
        sacc[n][r] = p;
        rs += p;
      }
#pragma unroll
      for (int d = 1; d < 16; d <<= 1) rs += __shfl_xor(rs, d);
      lsum[r] = lsum[r] * alpha + rs;
#pragma unroll
      for (int n = 0; n < 8; ++n) o[n][r] *= alpha;
    }
    // P -> bf16 -> per-wave LDS ([16][72] padded: 2-way max on b128 reads)
    u16* pl = &Plds[w][0];
#pragma unroll
    for (int n = 0; n < 4; ++n)
#pragma unroll
      for (int r = 0; r < 4; ++r)
        pl[(lg * 4 + r) * 72 + n * 16 + ll] = f2bf(sacc[n][r]);
    // O += P V   (A = P[16][64], B from Vt tile)
#pragma unroll
    for (int kc = 0; kc < 2; ++kc) {
      short8 pa = *(const short8*)((const char*)&Plds[w][0] + ll * 144 + kc * 64 + lg * 16);
#pragma unroll
      for (int n = 0; n < 8; ++n) {
        int rowb = n * 16 + ll;
        short8 vb = *(const short8*)((const char*)Vlds + rowb * 128 +
                                     ((kc * 64 + lg * 16) ^ ((rowb & 7) << 4)));
        o[n] = MFMA_BF16(pa, vb, o[n]);
      }
    }
  }

  float* ob = out + (size_t)(bi * 4096 + q0 + lg * 4) * 128 + ll;
#pragma unroll
  for (int r = 0; r < 4; ++r) {
    float inv = 1.0f / lsum[r];
#pragma unroll
    for (int n = 0; n < 8; ++n) ob[(size_t)r * 128 + n * 16] = o[n][r] * inv;
  }
}

// ---------------------------------------------------------------------------
extern "C" void kernel_launch(void* const* d_in, const int* in_sizes, int n_in,
                              void* d_out, int out_size, void* d_ws, size_t ws_size,
                              hipStream_t stream) {
  (void)in_sizes; (void)n_in; (void)out_size; (void)ws_size;
  const float* x  = (const float*)d_in[0];
  const float* Wq = (const float*)d_in[1];
  const float* Wk = (const float*)d_in[2];
  const float* Wv = (const float*)d_in[3];
  float* out = (float*)d_out;
  char* ws = (char*)d_ws;
  u16* qws  = (u16*)(ws);                  // 4 MiB  [B*T][128] bf16 (scaled)
  u16* kws  = (u16*)(ws + (4u << 20));     // 4 MiB  [B*T][128] bf16
  u16* vtws = (u16*)(ws + (8u << 20));     // 4 MiB  [B][128][T] bf16
  u16* Wb   = (u16*)(ws + (12u << 20));    // 768 KiB [384][1024] bf16

  wconv_kernel<<<dim3(192), dim3(256), 0, stream>>>(Wq, Wk, Wv, Wb);
  qkv_proj_kernel<<<dim3(256), dim3(256), 0, stream>>>(x, Wb, qws, kws, vtws);
  attn_kernel<<<dim3(512), dim3(128), 0, stream>>>(qws, kws, vtws, out);
}

// Round 2
// 134.255 us; speedup vs baseline: 1.3901x; 1.3901x over previous
//
#include <hip/hip_runtime.h>

// ---------------------------------------------------------------------------
// Attention fused kernel for MI355X (gfx950)
//   x:[4,4096,1024] f32, Wq/Wk/Wv:[128,1024] f32 -> out:[4,4096,128] f32
// Round 1: attn = KV-split-4 + double-buffered K staging with counted vmcnt
//          (never drain to 0 in-loop), V drain hidden under QK+softmax.
//          qkv_proj = 8-wave blocks (4 row-groups x 2 col-halves).
// ws: [0,4M) q bf16 (pre-scaled by log2e/sqrt(128)), [4M,8M) k bf16,
//     [8M,12M) v^T bf16 [B][128][T], [12M,12.75M) W bf16,
//     [13M,46.5M) o partials f32 [4][16384][128], [47M,47.5M) m,l partials.
// ---------------------------------------------------------------------------

typedef __attribute__((ext_vector_type(8))) short short8;
typedef __attribute__((ext_vector_type(8))) unsigned short ushort8;
typedef __attribute__((ext_vector_type(4))) unsigned short ushort4v;
typedef __attribute__((ext_vector_type(4))) float f32x4;
typedef unsigned int u32;
typedef unsigned short u16;

#define MFMA_BF16(a, b, c) __builtin_amdgcn_mfma_f32_16x16x32_bf16((a), (b), (c), 0, 0, 0)
#define WAITVM(n) asm volatile("s_waitcnt vmcnt(" #n ")" ::: "memory")

__device__ __forceinline__ void gload16(const void* g, void* l) {
  __builtin_amdgcn_global_load_lds((const __attribute__((address_space(1))) u32*)g,
                                   (__attribute__((address_space(3))) u32*)l, 16, 0, 0);
}

__device__ __forceinline__ u16 f2bf(float f) {  // f32 -> bf16 bits, RNE
  u32 u = __builtin_bit_cast(u32, f);
  u = u + 0x7FFFu + ((u >> 16) & 1u);
  return (u16)(u >> 16);
}

__device__ __forceinline__ short8 cvt8(const float* p) {  // 8 f32 -> bf16x8 frag
  float4 a = *(const float4*)p;
  float4 b = *(const float4*)(p + 4);
  short8 v;
  v[0] = (short)f2bf(a.x); v[1] = (short)f2bf(a.y);
  v[2] = (short)f2bf(a.z); v[3] = (short)f2bf(a.w);
  v[4] = (short)f2bf(b.x); v[5] = (short)f2bf(b.y);
  v[6] = (short)f2bf(b.z); v[7] = (short)f2bf(b.w);
  return v;
}

// ---------------- kernel 0: W f32 -> bf16 (Wb[384][1024]) -------------------
__global__ __launch_bounds__(256) void wconv_kernel(const float* __restrict__ Wq,
                                                    const float* __restrict__ Wk,
                                                    const float* __restrict__ Wv,
                                                    u16* __restrict__ Wb) {
  int g = (blockIdx.x * 256 + threadIdx.x) * 8;
  const float* src;
  if (g < 131072)      src = Wq + g;
  else if (g < 262144) src = Wk + (g - 131072);
  else                 src = Wv + (g - 262144);
  float4 a = *(const float4*)src;
  float4 b = *(const float4*)(src + 4);
  ushort8 o;
  o[0] = f2bf(a.x); o[1] = f2bf(a.y); o[2] = f2bf(a.z); o[3] = f2bf(a.w);
  o[4] = f2bf(b.x); o[5] = f2bf(b.y); o[6] = f2bf(b.z); o[7] = f2bf(b.w);
  *(ushort8*)(Wb + g) = o;
}

// ---------------- kernel 1: fused QKV projection ----------------------------
// 512 thr = 8 waves: rg = w>>1 picks 16-row group, cs = w&1 picks 12 n-tiles.
#define QK_SCALE 0.127517446f  // (1/sqrt(128)) * log2(e)

__global__ __launch_bounds__(512) void qkv_proj_kernel(const float* __restrict__ x,
                                                       const u16* __restrict__ Wb,
                                                       u16* __restrict__ qout,
                                                       u16* __restrict__ kout,
                                                       u16* __restrict__ vtout) {
  __shared__ __align__(16) unsigned char Wlds[49152];  // 384*64*2, 16B-chunk swz
  const int tid = threadIdx.x;
  const int w = tid >> 6;
  const int l = tid & 63;
  const int lg = l >> 4, ll = l & 15;
  const int rg = w >> 1, cs = w & 1;
  const int m0 = blockIdx.x * 64;

  f32x4 acc[12];
#pragma unroll
  for (int t = 0; t < 12; ++t) acc[t] = f32x4{0.f, 0.f, 0.f, 0.f};

  const float* xr = x + (size_t)(m0 + rg * 16 + ll) * 1024 + lg * 8;

  for (int k0 = 0; k0 < 1024; k0 += 64) {
    __syncthreads();  // protect Wlds from previous iteration's readers
#pragma unroll
    for (int c = 0; c < 6; ++c) {  // 3072 16B chunks / 512 thr
      int L = c * 512 + tid;
      int row = L >> 3, chp = L & 7;
      int gch = chp ^ (row & 7);  // pre-swizzled global source
      gload16((const char*)Wb + row * 2048 + k0 * 2 + gch * 16,
              Wlds + c * 8192 + w * 1024);
    }
    __syncthreads();  // drains vmcnt
    short8 a0 = cvt8(xr + k0);
    short8 a1 = cvt8(xr + k0 + 32);
#pragma unroll
    for (int t = 0; t < 12; ++t) {
      int row = (cs * 12 + t) * 16 + ll;
      const char* base = (const char*)Wlds + row * 128;
      int sw = (row & 7) << 4;
      acc[t] = MFMA_BF16(a0, *(const short8*)(base + ((lg * 16) ^ sw)), acc[t]);
      acc[t] = MFMA_BF16(a1, *(const short8*)(base + ((64 + lg * 16) ^ sw)), acc[t]);
    }
  }

  const int rbase = m0 + rg * 16 + lg * 4;
#pragma unroll
  for (int t = 0; t < 12; ++t) {
    int tg = cs * 12 + t;
    if (tg < 8) {
#pragma unroll
      for (int r = 0; r < 4; ++r)
        qout[(size_t)(rbase + r) * 128 + tg * 16 + ll] = f2bf(acc[t][r] * QK_SCALE);
    } else if (tg < 16) {
#pragma unroll
      for (int r = 0; r < 4; ++r)
        kout[(size_t)(rbase + r) * 128 + (tg - 8) * 16 + ll] = f2bf(acc[t][r]);
    } else {
      int d = (tg - 16) * 16 + ll;
      ushort4v o;
#pragma unroll
      for (int r = 0; r < 4; ++r) o[r] = f2bf(acc[t][r]);
      *(ushort4v*)&vtout[(size_t)((rbase >> 12) * 128 + d) * 4096 + (rbase & 4095)] = o;
    }
  }
}

// ---------------- kernel 2: causal flash attention --------------------------
// NSPLIT-way KV split; 128 thr = 2 waves x 16 q-rows (32-row tile).
// K double-buffered (prefetch s+1 before compute s, counted vmcnt);
// V single-buffered (drain hidden under QK+softmax). 3 raw barriers/step.
#define NEG_INF (-1e30f)

__device__ __forceinline__ void stage_k(const char* kbatch, unsigned char* Kl,
                                        int kv0, int tid, int w) {
#pragma unroll
  for (int c = 0; c < 8; ++c) {
    int L = c * 128 + tid;
    int row = L >> 4, chp = L & 15;
    int gch = chp ^ (row & 7);
    gload16(kbatch + (size_t)(kv0 + row) * 256 + gch * 16, Kl + c * 2048 + w * 1024);
  }
}
__device__ __forceinline__ void stage_v(const char* vbatch, unsigned char* Vl,
                                        int kv0, int tid, int w) {
#pragma unroll
  for (int c = 0; c < 8; ++c) {
    int L = c * 128 + tid;
    int row = L >> 3, chp = L & 7;
    int gch = chp ^ (row & 7);
    gload16(vbatch + (size_t)row * 8192 + kv0 * 2 + gch * 16, Vl + c * 2048 + w * 1024);
  }
}

template <int NSPLIT>
__global__ __launch_bounds__(128) void attn_kernel(const u16* __restrict__ qws,
                                                   const u16* __restrict__ kws,
                                                   const u16* __restrict__ vtws,
                                                   float* __restrict__ out,
                                                   float* __restrict__ opart,
                                                   float* __restrict__ mlpart) {
  __shared__ __align__(16) unsigned char Klds[2][16384];  // [64 kv][128 d] swz
  __shared__ __align__(16) unsigned char Vlds[16384];     // [128 d][64 kv] swz
  __shared__ __align__(16) u16 Plds[2][1152];             // per wave [16][72]

  const int tid = threadIdx.x;
  const int w = tid >> 6;
  const int l = tid & 63;
  const int lg = l >> 4, ll = l & 15;
  const int bid = (int)blockIdx.x;
  const int sp = bid & (NSPLIT - 1);
  const int tb = bid / NSPLIT;
  const int bi = tb & 3;
  const int qt = 127 - (tb >> 2);  // reversed: long tiles first
  const int q0 = qt * 32 + w * 16;
  const int grow = bi * 4096 + q0 + lg * 4;  // first of this lane's 4 rows

  const int nsteps = (qt >> 1) + 1;
  const int s_lo = (nsteps * sp) / NSPLIT;
  const int s_hi = (nsteps * (sp + 1)) / NSPLIT;

  if constexpr (NSPLIT > 1) {
    if (s_lo >= s_hi) {  // empty split: mark and exit (block-uniform)
      if (ll == 0) {
#pragma unroll
        for (int r = 0; r < 4; ++r) {
          mlpart[sp * 16384 + grow + r] = NEG_INF;           // m
          mlpart[NSPLIT * 16384 + sp * 16384 + grow + r] = 0.f;  // l
        }
      }
      return;
    }
  }

  short8 qa[4];
  const u16* qbase = qws + (size_t)(bi * 4096 + q0 + ll) * 128 + lg * 8;
#pragma unroll
  for (int kc = 0; kc < 4; ++kc) qa[kc] = *(const short8*)(qbase + kc * 32);

  f32x4 o[8];
#pragma unroll
  for (int n = 0; n < 8; ++n) o[n] = f32x4{0.f, 0.f, 0.f, 0.f};
  float m[4] = {NEG_INF, NEG_INF, NEG_INF, NEG_INF};
  float lsum[4] = {0.f, 0.f, 0.f, 0.f};

  const char* kbatch = (const char*)kws + (size_t)bi * 4096 * 256;
  const char* vbatch = (const char*)vtws + (size_t)bi * 128 * 8192;

  stage_k(kbatch, Klds[0], s_lo * 64, tid, w);  // prologue: K(s_lo), 8 loads
  int cur = 0;

  for (int s = s_lo; s < s_hi; ++s) {
    const int kv0 = s * 64;
    // entry: K(s) in flight (8). Issue V(s), then prefetch K(s+1).
    stage_v(vbatch, Vlds, kv0, tid, w);                   // +8 -> 16
    const bool more = (s + 1 < s_hi);
    if (more) {
      stage_k(kbatch, Klds[cur ^ 1], kv0 + 64, tid, w);   // +8 -> 24
      WAITVM(16);  // K(s) landed; V(s)+K(s+1) in flight
    } else {
      WAITVM(8);   // K(s) landed; V(s) in flight
    }
    __builtin_amdgcn_s_barrier();
    __builtin_amdgcn_sched_barrier(0);

    // S = Q K^T
    const unsigned char* Kl = Klds[cur];
    f32x4 sacc[4];
#pragma unroll
    for (int n = 0; n < 4; ++n) sacc[n] = f32x4{0.f, 0.f, 0.f, 0.f};
#pragma unroll
    for (int n = 0; n < 4; ++n) {
      int rowb = n * 16 + ll;
      const char* kr = (const char*)Kl + rowb * 256;
      int sw = (rowb & 7) << 4;
#pragma unroll
      for (int kc = 0; kc < 4; ++kc) {
        short8 kb = *(const short8*)(kr + ((kc * 64 + lg * 16) ^ sw));
        sacc[n] = MFMA_BF16(qa[kc], kb, sacc[n]);
      }
    }
    if (kv0 + 63 > q0) {  // causal mask near diagonal (wave-uniform branch)
#pragma unroll
      for (int n = 0; n < 4; ++n)
#pragma unroll
        for (int r = 0; r < 4; ++r)
          if (kv0 + n * 16 + ll > q0 + lg * 4 + r) sacc[n][r] = NEG_INF;
    }
    // online softmax (exp2 domain)
#pragma unroll
    for (int r = 0; r < 4; ++r) {
      float mx = fmaxf(fmaxf(sacc[0][r], sacc[1][r]), fmaxf(sacc[2][r], sacc[3][r]));
#pragma unroll
      for (int d = 1; d < 16; d <<= 1) mx = fmaxf(mx, __shfl_xor(mx, d));
      float mn = fmaxf(m[r], mx);
      float alpha = exp2f(m[r] - mn);
      m[r] = mn;
      float rs = 0.f;
#pragma unroll
      for (int n = 0; n < 4; ++n) {
        float p = exp2f(sacc[n][r] - mn);
        sacc[n][r] = p;
        rs += p;
      }
#pragma unroll
      for (int d = 1; d < 16; d <<= 1) rs += __shfl_xor(rs, d);
      lsum[r] = lsum[r] * alpha + rs;
#pragma unroll
      for (int n = 0; n < 8; ++n) o[n][r] *= alpha;
    }
    // P -> bf16 -> per-wave LDS
    u16* pl = &Plds[w][0];
#pragma unroll
    for (int n = 0; n < 4; ++n)
#pragma unroll
      for (int r = 0; r < 4; ++r)
        pl[(lg * 4 + r) * 72 + n * 16 + ll] = f2bf(sacc[n][r]);

    if (more) { WAITVM(8); } else { WAITVM(0); }  // V(s) landed
    __builtin_amdgcn_s_barrier();
    __builtin_amdgcn_sched_barrier(0);

    // O += P V
#pragma unroll
    for (int kc = 0; kc < 2; ++kc) {
      short8 pa = *(const short8*)((const char*)&Plds[w][0] + ll * 144 + kc * 64 + lg * 16);
#pragma unroll
      for (int n = 0; n < 8; ++n) {
        int rowb = n * 16 + ll;
        short8 vb = *(const short8*)((const char*)Vlds + rowb * 128 +
                                     ((kc * 64 + lg * 16) ^ ((rowb & 7) << 4)));
        o[n] = MFMA_BF16(pa, vb, o[n]);
      }
    }
    __builtin_amdgcn_s_barrier();  // PV done before next iter's V overwrite
    cur ^= 1;
  }

  if constexpr (NSPLIT == 1) {
    float* ob = out + (size_t)grow * 128 + ll;
#pragma unroll
    for (int r = 0; r < 4; ++r) {
      float inv = 1.0f / lsum[r];
#pragma unroll
      for (int n = 0; n < 8; ++n) ob[(size_t)r * 128 + n * 16] = o[n][r] * inv;
    }
  } else {
    float* ob = opart + ((size_t)sp * 16384 + grow) * 128 + ll;
#pragma unroll
    for (int r = 0; r < 4; ++r)
#pragma unroll
      for (int n = 0; n < 8; ++n) ob[(size_t)r * 128 + n * 16] = o[n][r];
    if (ll == 0) {
#pragma unroll
      for (int r = 0; r < 4; ++r) {
        mlpart[sp * 16384 + grow + r] = m[r];
        mlpart[NSPLIT * 16384 + sp * 16384 + grow + r] = lsum[r];
      }
    }
  }
}

// ---------------- kernel 3: split combine -----------------------------------
__global__ __launch_bounds__(256) void combine_kernel(const float* __restrict__ opart,
                                                      const float* __restrict__ mlpart,
                                                      float* __restrict__ out) {
  int idx = blockIdx.x * 256 + threadIdx.x;  // 16384*128 threads
  int row = idx >> 7;
  float m0 = mlpart[row], m1 = mlpart[16384 + row];
  float m2 = mlpart[32768 + row], m3 = mlpart[49152 + row];
  float M = fmaxf(fmaxf(m0, m1), fmaxf(m2, m3));
  float s0 = exp2f(m0 - M), s1 = exp2f(m1 - M);
  float s2 = exp2f(m2 - M), s3 = exp2f(m3 - M);
  const float* lp = mlpart + 65536;
  float L = lp[row] * s0 + lp[16384 + row] * s1 + lp[32768 + row] * s2 + lp[49152 + row] * s3;
  size_t o = (size_t)idx;
  float O = opart[o] * s0 + opart[o + 2097152] * s1 +
            opart[o + 4194304] * s2 + opart[o + 6291456] * s3;
  out[o] = O / L;
}

// ---------------------------------------------------------------------------
extern "C" void kernel_launch(void* const* d_in, const int* in_sizes, int n_in,
                              void* d_out, int out_size, void* d_ws, size_t ws_size,
                              hipStream_t stream) {
  (void)in_sizes; (void)n_in; (void)out_size;
  const float* x  = (const float*)d_in[0];
  const float* Wq = (const float*)d_in[1];
  const float* Wk = (const float*)d_in[2];
  const float* Wv = (const float*)d_in[3];
  float* out = (float*)d_out;
  char* ws = (char*)d_ws;
  u16* qws  = (u16*)(ws);
  u16* kws  = (u16*)(ws + (4u << 20));
  u16* vtws = (u16*)(ws + (8u << 20));
  u16* Wb   = (u16*)(ws + (12u << 20));
  float* opart  = (float*)(ws + (13u << 20));   // 33.5 MiB
  float* mlpart = (float*)(ws + (47u << 20));   // 512 KiB

  wconv_kernel<<<dim3(192), dim3(256), 0, stream>>>(Wq, Wk, Wv, Wb);
  qkv_proj_kernel<<<dim3(256), dim3(512), 0, stream>>>(x, Wb, qws, kws, vtws);
  if (ws_size >= ((size_t)48 << 20)) {
    attn_kernel<4><<<dim3(2048), dim3(128), 0, stream>>>(qws, kws, vtws, nullptr, opart, mlpart);
    combine_kernel<<<dim3(8192), dim3(256), 0, stream>>>(opart, mlpart, out);
  } else {
    attn_kernel<1><<<dim3(512), dim3(128), 0, stream>>>(qws, kws, vtws, out, nullptr, nullptr);
  }
}

// Round 3
// 115.736 us; speedup vs baseline: 1.6125x; 1.1600x over previous
//
#include <hip/hip_runtime.h>

// ---------------------------------------------------------------------------
// Attention fused kernel for MI355X (gfx950)
//   x:[4,4096,1024] f32, Wq/Wk/Wv:[128,1024] f32 -> out:[4,4096,128] f32
// Round 2: attn = 8-wave blocks (128-row q-tile, 16 waves/CU), K dbuf with
//          counted vmcnt, per-wave active-guard for fully-masked tiles.
//          qkv = N-split-3 (q/k/v), W dbuf, 1 barrier/step, 5 blocks/CU.
// ws: [0,4M) q bf16 (pre-scaled by log2e/sqrt(128)), [4M,8M) k bf16,
//     [8M,12M) v^T bf16 [B][128][T], [12M,12.75M) W bf16,
//     [13M,46.5M) o partials f32 [4][16384][128], [47M,47.5M) m,l partials.
// ---------------------------------------------------------------------------

typedef __attribute__((ext_vector_type(8))) short short8;
typedef __attribute__((ext_vector_type(8))) unsigned short ushort8;
typedef __attribute__((ext_vector_type(4))) unsigned short ushort4v;
typedef __attribute__((ext_vector_type(4))) float f32x4;
typedef unsigned int u32;
typedef unsigned short u16;

#define MFMA_BF16(a, b, c) __builtin_amdgcn_mfma_f32_16x16x32_bf16((a), (b), (c), 0, 0, 0)
#define WAITVM(n) asm volatile("s_waitcnt vmcnt(" #n ")" ::: "memory")

__device__ __forceinline__ void gload16(const void* g, void* l) {
  __builtin_amdgcn_global_load_lds((const __attribute__((address_space(1))) u32*)g,
                                   (__attribute__((address_space(3))) u32*)l, 16, 0, 0);
}

__device__ __forceinline__ u16 f2bf(float f) {  // f32 -> bf16 bits, RNE
  u32 u = __builtin_bit_cast(u32, f);
  u = u + 0x7FFFu + ((u >> 16) & 1u);
  return (u16)(u >> 16);
}

__device__ __forceinline__ short8 cvt8(const float* p) {  // 8 f32 -> bf16x8 frag
  float4 a = *(const float4*)p;
  float4 b = *(const float4*)(p + 4);
  short8 v;
  v[0] = (short)f2bf(a.x); v[1] = (short)f2bf(a.y);
  v[2] = (short)f2bf(a.z); v[3] = (short)f2bf(a.w);
  v[4] = (short)f2bf(b.x); v[5] = (short)f2bf(b.y);
  v[6] = (short)f2bf(b.z); v[7] = (short)f2bf(b.w);
  return v;
}

// ---------------- kernel 0: W f32 -> bf16 (Wb[384][1024]) -------------------
__global__ __launch_bounds__(256) void wconv_kernel(const float* __restrict__ Wq,
                                                    const float* __restrict__ Wk,
                                                    const float* __restrict__ Wv,
                                                    u16* __restrict__ Wb) {
  int g = (blockIdx.x * 256 + threadIdx.x) * 8;
  const float* src;
  if (g < 131072)      src = Wq + g;
  else if (g < 262144) src = Wk + (g - 131072);
  else                 src = Wv + (g - 262144);
  float4 a = *(const float4*)src;
  float4 b = *(const float4*)(src + 4);
  ushort8 o;
  o[0] = f2bf(a.x); o[1] = f2bf(a.y); o[2] = f2bf(a.z); o[3] = f2bf(a.w);
  o[4] = f2bf(b.x); o[5] = f2bf(b.y); o[6] = f2bf(b.z); o[7] = f2bf(b.w);
  *(ushort8*)(Wb + g) = o;
}

// ---------------- kernel 1: fused QKV projection ----------------------------
// grid 768: ns = bx%3 (0:q 1:k 2:v), m0 = (bx/3)*64. 256 thr = 4 waves x 16 rows.
// W slice [128 rows][64 k] double-buffered; ONE barrier per k-step.
#define QK_SCALE 0.127517446f  // (1/sqrt(128)) * log2(e)

__global__ __launch_bounds__(256) void qkv_proj_kernel(const float* __restrict__ x,
                                                       const u16* __restrict__ Wb,
                                                       u16* __restrict__ qout,
                                                       u16* __restrict__ kout,
                                                       u16* __restrict__ vtout) {
  __shared__ __align__(16) unsigned char Wlds[2][16384];  // [128][64] bf16, swz
  const int tid = threadIdx.x;
  const int w = tid >> 6;
  const int l = tid & 63;
  const int lg = l >> 4, ll = l & 15;
  const int ns = (int)blockIdx.x % 3;
  const int m0 = ((int)blockIdx.x / 3) * 64;
  const u16* Ws = Wb + ns * 128 * 1024;  // this split's 128 W rows

  f32x4 acc[8];
#pragma unroll
  for (int t = 0; t < 8; ++t) acc[t] = f32x4{0.f, 0.f, 0.f, 0.f};

  const float* xr = x + (size_t)(m0 + w * 16 + ll) * 1024 + lg * 8;

  // stage W k-slice ks into buf: 1024 chunks / 256 thr = 4 each
#define STAGE_W(buf, ks)                                                       \
  {                                                                            \
    _Pragma("unroll") for (int c = 0; c < 4; ++c) {                            \
      int L = c * 256 + tid;                                                   \
      int row = L >> 3, chp = L & 7;                                           \
      int gch = chp ^ (row & 7);                                               \
      gload16((const char*)Ws + row * 2048 + (ks) * 128 + gch * 16,            \
              (unsigned char*)Wlds[buf] + c * 4096 + w * 1024);                \
    }                                                                          \
  }

  STAGE_W(0, 0);
  int cur = 0;
  for (int ks = 0; ks < 16; ++ks) {
    WAITVM(0);                       // W(ks) landed
    __builtin_amdgcn_s_barrier();    // all waves see full tile; prev reads done
    __builtin_amdgcn_sched_barrier(0);
    if (ks < 15) STAGE_W(cur ^ 1, ks + 1);  // overlaps with MFMA below
    short8 a0 = cvt8(xr + ks * 64);
    short8 a1 = cvt8(xr + ks * 64 + 32);
    const char* base0 = (const char*)Wlds[cur];
    __builtin_amdgcn_s_setprio(1);
#pragma unroll
    for (int t = 0; t < 8; ++t) {
      int row = t * 16 + ll;
      const char* base = base0 + row * 128;
      int sw = (row & 7) << 4;
      acc[t] = MFMA_BF16(a0, *(const short8*)(base + ((lg * 16) ^ sw)), acc[t]);
      acc[t] = MFMA_BF16(a1, *(const short8*)(base + ((64 + lg * 16) ^ sw)), acc[t]);
    }
    __builtin_amdgcn_s_setprio(0);
    cur ^= 1;
  }

  const int rbase = m0 + w * 16 + lg * 4;
  if (ns == 0) {
#pragma unroll
    for (int t = 0; t < 8; ++t)
#pragma unroll
      for (int r = 0; r < 4; ++r)
        qout[(size_t)(rbase + r) * 128 + t * 16 + ll] = f2bf(acc[t][r] * QK_SCALE);
  } else if (ns == 1) {
#pragma unroll
    for (int t = 0; t < 8; ++t)
#pragma unroll
      for (int r = 0; r < 4; ++r)
        kout[(size_t)(rbase + r) * 128 + t * 16 + ll] = f2bf(acc[t][r]);
  } else {
#pragma unroll
    for (int t = 0; t < 8; ++t) {
      int d = t * 16 + ll;
      ushort4v o;
#pragma unroll
      for (int r = 0; r < 4; ++r) o[r] = f2bf(acc[t][r]);
      *(ushort4v*)&vtout[(size_t)((rbase >> 12) * 128 + d) * 4096 + (rbase & 4095)] = o;
    }
  }
#undef STAGE_W
}

// ---------------- kernel 2: causal flash attention --------------------------
// 512 thr = 8 waves x 16 q-rows (128-row tile). NSPLIT-way KV split.
// K dbuf (counted vmcnt), V single-buffered; per-wave active-guard skips
// compute on fully-masked tiles (but always executes WAITVM + barriers).
#define NEG_INF (-1e30f)

__device__ __forceinline__ void stage_k8(const char* kbatch, unsigned char* Kl,
                                         int kv0, int tid, int w) {
#pragma unroll
  for (int c = 0; c < 2; ++c) {
    int L = c * 512 + tid;
    int row = L >> 4, chp = L & 15;
    int gch = chp ^ (row & 7);
    gload16(kbatch + (size_t)(kv0 + row) * 256 + gch * 16, Kl + c * 8192 + w * 1024);
  }
}
__device__ __forceinline__ void stage_v8(const char* vbatch, unsigned char* Vl,
                                         int kv0, int tid, int w) {
#pragma unroll
  for (int c = 0; c < 2; ++c) {
    int L = c * 512 + tid;
    int row = L >> 3, chp = L & 7;
    int gch = chp ^ (row & 7);
    gload16(vbatch + (size_t)row * 8192 + kv0 * 2 + gch * 16, Vl + c * 8192 + w * 1024);
  }
}

template <int NSPLIT>
__global__ __launch_bounds__(512, 4) void attn_kernel(const u16* __restrict__ qws,
                                                      const u16* __restrict__ kws,
                                                      const u16* __restrict__ vtws,
                                                      float* __restrict__ out,
                                                      float* __restrict__ opart,
                                                      float* __restrict__ mlpart) {
  __shared__ __align__(16) unsigned char Klds[2][16384];  // [64 kv][128 d] swz
  __shared__ __align__(16) unsigned char Vlds[16384];     // [128 d][64 kv] swz
  __shared__ __align__(16) u16 Plds[8][1152];             // per wave [16][72]

  const int tid = threadIdx.x;
  const int w = tid >> 6;
  const int l = tid & 63;
  const int lg = l >> 4, ll = l & 15;
  const int bid = (int)blockIdx.x;
  const int sp = bid & (NSPLIT - 1);
  const int tb = bid / NSPLIT;
  const int bi = tb & 3;
  const int qt = 31 - (tb >> 2);   // reversed: long tiles first
  const int q0 = qt * 128 + w * 16;
  const int grow = bi * 4096 + q0 + lg * 4;

  const int nsteps = qt * 2 + 2;
  const int s_lo = (nsteps * sp) / NSPLIT;
  const int s_hi = (nsteps * (sp + 1)) / NSPLIT;

  if constexpr (NSPLIT > 1) {
    if (s_lo >= s_hi) {  // empty split: mark and exit (block-uniform)
      if (ll == 0) {
#pragma unroll
        for (int r = 0; r < 4; ++r) {
          mlpart[sp * 16384 + grow + r] = NEG_INF;
          mlpart[NSPLIT * 16384 + sp * 16384 + grow + r] = 0.f;
        }
      }
      return;
    }
  }

  short8 qa[4];
  const u16* qbase = qws + (size_t)(bi * 4096 + q0 + ll) * 128 + lg * 8;
#pragma unroll
  for (int kc = 0; kc < 4; ++kc) qa[kc] = *(const short8*)(qbase + kc * 32);

  f32x4 o[8];
#pragma unroll
  for (int n = 0; n < 8; ++n) o[n] = f32x4{0.f, 0.f, 0.f, 0.f};
  float m[4] = {NEG_INF, NEG_INF, NEG_INF, NEG_INF};
  float lsum[4] = {0.f, 0.f, 0.f, 0.f};

  const char* kbatch = (const char*)kws + (size_t)bi * 4096 * 256;
  const char* vbatch = (const char*)vtws + (size_t)bi * 128 * 8192;

  stage_k8(kbatch, Klds[0], s_lo * 64, tid, w);  // prologue: 2 loads in flight
  int cur = 0;

  for (int s = s_lo; s < s_hi; ++s) {
    const int kv0 = s * 64;
    stage_v8(vbatch, Vlds, kv0, tid, w);                  // +2 -> 4
    const bool more = (s + 1 < s_hi);
    if (more) {
      stage_k8(kbatch, Klds[cur ^ 1], kv0 + 64, tid, w);  // +2 -> 6
      WAITVM(4);  // K(s) landed
    } else {
      WAITVM(2);
    }
    __builtin_amdgcn_s_barrier();
    __builtin_amdgcn_sched_barrier(0);

    const bool active = (kv0 <= q0 + 15);  // wave-uniform
    f32x4 sacc[4];
    if (active) {
      // S = Q K^T
#pragma unroll
      for (int n = 0; n < 4; ++n) sacc[n] = f32x4{0.f, 0.f, 0.f, 0.f};
      const unsigned char* Kl = Klds[cur];
      __builtin_amdgcn_s_setprio(1);
#pragma unroll
      for (int n = 0; n < 4; ++n) {
        int rowb = n * 16 + ll;
        const char* kr = (const char*)Kl + rowb * 256;
        int sw = (rowb & 7) << 4;
#pragma unroll
        for (int kc = 0; kc < 4; ++kc) {
          short8 kb = *(const short8*)(kr + ((kc * 64 + lg * 16) ^ sw));
          sacc[n] = MFMA_BF16(qa[kc], kb, sacc[n]);
        }
      }
      __builtin_amdgcn_s_setprio(0);
      if (kv0 + 63 > q0) {  // causal mask near diagonal
#pragma unroll
        for (int n = 0; n < 4; ++n)
#pragma unroll
          for (int r = 0; r < 4; ++r)
            if (kv0 + n * 16 + ll > q0 + lg * 4 + r) sacc[n][r] = NEG_INF;
      }
      // online softmax (exp2 domain)
#pragma unroll
      for (int r = 0; r < 4; ++r) {
        float mx = fmaxf(fmaxf(sacc[0][r], sacc[1][r]), fmaxf(sacc[2][r], sacc[3][r]));
#pragma unroll
        for (int d = 1; d < 16; d <<= 1) mx = fmaxf(mx, __shfl_xor(mx, d));
        float mn = fmaxf(m[r], mx);
        float alpha = exp2f(m[r] - mn);
        m[r] = mn;
        float rs = 0.f;
#pragma unroll
        for (int n = 0; n < 4; ++n) {
          float p = exp2f(sacc[n][r] - mn);
          sacc[n][r] = p;
          rs += p;
        }
#pragma unroll
        for (int d = 1; d < 16; d <<= 1) rs += __shfl_xor(rs, d);
        lsum[r] = lsum[r] * alpha + rs;
#pragma unroll
        for (int n = 0; n < 8; ++n) o[n][r] *= alpha;
      }
      // P -> bf16 -> per-wave LDS
      u16* pl = &Plds[w][0];
#pragma unroll
      for (int n = 0; n < 4; ++n)
#pragma unroll
        for (int r = 0; r < 4; ++r)
          pl[(lg * 4 + r) * 72 + n * 16 + ll] = f2bf(sacc[n][r]);
    }

    if (more) { WAITVM(2); } else { WAITVM(0); }  // V(s) landed
    __builtin_amdgcn_s_barrier();
    __builtin_amdgcn_sched_barrier(0);

    if (active) {
      // O += P V
      __builtin_amdgcn_s_setprio(1);
#pragma unroll
      for (int kc = 0; kc < 2; ++kc) {
        short8 pa = *(const short8*)((const char*)&Plds[w][0] + ll * 144 + kc * 64 + lg * 16);
#pragma unroll
        for (int n = 0; n < 8; ++n) {
          int rowb = n * 16 + ll;
          short8 vb = *(const short8*)((const char*)Vlds + rowb * 128 +
                                       ((kc * 64 + lg * 16) ^ ((rowb & 7) << 4)));
          o[n] = MFMA_BF16(pa, vb, o[n]);
        }
      }
      __builtin_amdgcn_s_setprio(0);
    }
    __builtin_amdgcn_s_barrier();  // V consumed before next iter's stage_v
    cur ^= 1;
  }

  if constexpr (NSPLIT == 1) {
    float* ob = out + (size_t)grow * 128 + ll;
#pragma unroll
    for (int r = 0; r < 4; ++r) {
      float inv = 1.0f / lsum[r];
#pragma unroll
      for (int n = 0; n < 8; ++n) ob[(size_t)r * 128 + n * 16] = o[n][r] * inv;
    }
  } else {
    float* ob = opart + ((size_t)sp * 16384 + grow) * 128 + ll;
#pragma unroll
    for (int r = 0; r < 4; ++r)
#pragma unroll
      for (int n = 0; n < 8; ++n) ob[(size_t)r * 128 + n * 16] = o[n][r];
    if (ll == 0) {
#pragma unroll
      for (int r = 0; r < 4; ++r) {
        mlpart[sp * 16384 + grow + r] = m[r];
        mlpart[NSPLIT * 16384 + sp * 16384 + grow + r] = lsum[r];
      }
    }
  }
}

// ---------------- kernel 3: split combine -----------------------------------
__global__ __launch_bounds__(256) void combine_kernel(const float* __restrict__ opart,
                                                      const float* __restrict__ mlpart,
                                                      float* __restrict__ out) {
  int idx = blockIdx.x * 256 + threadIdx.x;  // 16384*128 threads
  int row = idx >> 7;
  float m0 = mlpart[row], m1 = mlpart[16384 + row];
  float m2 = mlpart[32768 + row], m3 = mlpart[49152 + row];
  float M = fmaxf(fmaxf(m0, m1), fmaxf(m2, m3));
  float s0 = exp2f(m0 - M), s1 = exp2f(m1 - M);
  float s2 = exp2f(m2 - M), s3 = exp2f(m3 - M);
  const float* lp = mlpart + 65536;
  float L = lp[row] * s0 + lp[16384 + row] * s1 + lp[32768 + row] * s2 + lp[49152 + row] * s3;
  size_t o = (size_t)idx;
  float O = opart[o] * s0 + opart[o + 2097152] * s1 +
            opart[o + 4194304] * s2 + opart[o + 6291456] * s3;
  out[o] = O / L;
}

// ---------------------------------------------------------------------------
extern "C" void kernel_launch(void* const* d_in, const int* in_sizes, int n_in,
                              void* d_out, int out_size, void* d_ws, size_t ws_size,
                              hipStream_t stream) {
  (void)in_sizes; (void)n_in; (void)out_size;
  const float* x  = (const float*)d_in[0];
  const float* Wq = (const float*)d_in[1];
  const float* Wk = (const float*)d_in[2];
  const float* Wv = (const float*)d_in[3];
  float* out = (float*)d_out;
  char* ws = (char*)d_ws;
  u16* qws  = (u16*)(ws);
  u16* kws  = (u16*)(ws + (4u << 20));
  u16* vtws = (u16*)(ws + (8u << 20));
  u16* Wb   = (u16*)(ws + (12u << 20));
  float* opart  = (float*)(ws + (13u << 20));   // 33.5 MiB
  float* mlpart = (float*)(ws + (47u << 20));   // 512 KiB

  wconv_kernel<<<dim3(192), dim3(256), 0, stream>>>(Wq, Wk, Wv, Wb);
  qkv_proj_kernel<<<dim3(768), dim3(256), 0, stream>>>(x, Wb, qws, kws, vtws);
  if (ws_size >= ((size_t)48 << 20)) {
    attn_kernel<4><<<dim3(512), dim3(512), 0, stream>>>(qws, kws, vtws, nullptr, opart, mlpart);
    combine_kernel<<<dim3(8192), dim3(256), 0, stream>>>(opart, mlpart, out);
  } else {
    attn_kernel<1><<<dim3(128), dim3(512), 0, stream>>>(qws, kws, vtws, out, nullptr, nullptr);
  }
}

// Round 4
// 109.374 us; speedup vs baseline: 1.7063x; 1.0582x over previous
//
#include <hip/hip_runtime.h>

// ---------------------------------------------------------------------------
// Attention fused for MI355X (gfx950)
//   x:[4,4096,1024] f32, Wq/Wk/Wv:[128,1024] f32 -> out:[4,4096,128] f32
// Round 4: attn rewritten to 32x32x16 MFMA, swapped QK^T (S^T = K·Q^T) with
//          in-register softmax (lane owns one q-col), cvt_pk+shfl P->bf16
//          B-frags, defer-max THR=8, K/V double-buffer, 1 barrier/step.
//          qkv: x-read-once (M=64, 8 waves, N=384 full), W dbuf pipeline.
// ws: [0,4M) q bf16 (scaled by log2e/sqrt(128)), [4M,8M) k bf16,
//     [8M,12M) v^T bf16 [B][128][T], [12M,12.75M) W bf16,
//     [13M,46.5M) o partials f32 [4][16384][128], [47M,47.5M) m,l partials.
// ---------------------------------------------------------------------------

typedef __attribute__((ext_vector_type(8))) short short8;
typedef __attribute__((ext_vector_type(8))) unsigned short ushort8;
typedef __attribute__((ext_vector_type(4))) unsigned short ushort4v;
typedef __attribute__((ext_vector_type(4))) float f32x4;
typedef __attribute__((ext_vector_type(16))) float f32x16;
typedef __attribute__((ext_vector_type(4))) int int4v;
typedef unsigned int u32;
typedef unsigned short u16;

#define MFMA32(a, b, c) __builtin_amdgcn_mfma_f32_32x32x16_bf16((a), (b), (c), 0, 0, 0)
#define WAITVM0() asm volatile("s_waitcnt vmcnt(0)" ::: "memory")
#define NEG_INF (-1e30f)

__device__ __forceinline__ void gload16(const void* g, void* l) {
  __builtin_amdgcn_global_load_lds((const __attribute__((address_space(1))) u32*)g,
                                   (__attribute__((address_space(3))) u32*)l, 16, 0, 0);
}

__device__ __forceinline__ u16 f2bf(float f) {  // f32 -> bf16 bits, RNE
  u32 u = __builtin_bit_cast(u32, f);
  u = u + 0x7FFFu + ((u >> 16) & 1u);
  return (u16)(u >> 16);
}

__device__ __forceinline__ u32 cvtpk(float lo, float hi) {  // {bf16(lo),bf16(hi)}
  u32 r;
  asm("v_cvt_pk_bf16_f32 %0, %1, %2" : "=v"(r) : "v"(lo), "v"(hi));
  return r;
}

__device__ __forceinline__ short8 cvt8(const float* p) {  // 8 f32 -> bf16x8 frag
  float4 a = *(const float4*)p;
  float4 b = *(const float4*)(p + 4);
  short8 v;
  v[0] = (short)f2bf(a.x); v[1] = (short)f2bf(a.y);
  v[2] = (short)f2bf(a.z); v[3] = (short)f2bf(a.w);
  v[4] = (short)f2bf(b.x); v[5] = (short)f2bf(b.y);
  v[6] = (short)f2bf(b.z); v[7] = (short)f2bf(b.w);
  return v;
}

// ---------------- kernel 0: W f32 -> bf16 (Wb[384][1024]) -------------------
__global__ __launch_bounds__(256) void wconv_kernel(const float* __restrict__ Wq,
                                                    const float* __restrict__ Wk,
                                                    const float* __restrict__ Wv,
                                                    u16* __restrict__ Wb) {
  int g = (blockIdx.x * 256 + threadIdx.x) * 8;
  const float* src;
  if (g < 131072)      src = Wq + g;
  else if (g < 262144) src = Wk + (g - 131072);
  else                 src = Wv + (g - 262144);
  float4 a = *(const float4*)src;
  float4 b = *(const float4*)(src + 4);
  ushort8 o;
  o[0] = f2bf(a.x); o[1] = f2bf(a.y); o[2] = f2bf(a.z); o[3] = f2bf(a.w);
  o[4] = f2bf(b.x); o[5] = f2bf(b.y); o[6] = f2bf(b.z); o[7] = f2bf(b.w);
  *(ushort8*)(Wb + g) = o;
}

// ---------------- kernel 1: fused QKV projection ----------------------------
// grid 256 (M=64), 512 thr = 8 waves: mh = w>>2 (32-row half), ng = w&3
// (3 n-tiles of 32). W tile [384 n][64 k] bf16 dbuf, 1 barrier/step.
#define QK_SCALE 0.127517446f  // (1/sqrt(128)) * log2(e)

__global__ __launch_bounds__(512, 1) void qkv_proj_kernel(const float* __restrict__ x,
                                                          const u16* __restrict__ Wb,
                                                          u16* __restrict__ qout,
                                                          u16* __restrict__ kout,
                                                          u16* __restrict__ vtout) {
  __shared__ __align__(16) unsigned char Wlds[2][49152];  // [384][64] bf16 swz
  const int tid = threadIdx.x;
  const int w = tid >> 6;
  const int l = tid & 63;
  const int h = l >> 5, n32 = l & 31;
  const int mh = w >> 2, ng = w & 3;
  const int m0 = (int)blockIdx.x * 64 + mh * 32;

  f32x16 acc[3];
#pragma unroll
  for (int j = 0; j < 3; ++j)
#pragma unroll
    for (int r = 0; r < 16; ++r) acc[j][r] = 0.f;

  const float* xrow = x + (size_t)(m0 + n32) * 1024;  // A rows: lane&31

  // stage W k-slice ks (384 rows x 128B) : 3072 chunks / 512 thr = 6 each
#define STAGE_W(buf, ks)                                                       \
  {                                                                            \
    _Pragma("unroll") for (int c = 0; c < 6; ++c) {                            \
      int L = c * 512 + tid;                                                   \
      int row = L >> 3, chp = L & 7;                                           \
      int gch = chp ^ (row & 7);                                               \
      gload16((const char*)Wb + row * 2048 + (ks) * 128 + gch * 16,            \
              (unsigned char*)Wlds[buf] + c * 8192 + w * 1024);                \
    }                                                                          \
  }

  STAGE_W(0, 0);
  int cur = 0;
  for (int ks = 0; ks < 16; ++ks) {
    WAITVM0();                       // W(ks) landed (issued one phase ago)
    __builtin_amdgcn_s_barrier();    // everyone done reading W(ks-1)'s buffer
    __builtin_amdgcn_sched_barrier(0);
    if (ks < 15) STAGE_W(cur ^ 1, ks + 1);  // overlaps with MFMA below
    const char* base0 = (const char*)Wlds[cur];
    __builtin_amdgcn_s_setprio(1);
#pragma unroll
    for (int k16 = 0; k16 < 4; ++k16) {
      short8 a = cvt8(xrow + ks * 64 + k16 * 16 + h * 8);
#pragma unroll
      for (int j = 0; j < 3; ++j) {
        int nrow = (ng * 3 + j) * 32 + n32;
        short8 b = *(const short8*)(base0 + nrow * 128 +
                                    ((k16 * 32 + h * 16) ^ ((nrow & 7) << 4)));
        acc[j] = MFMA32(a, b, acc[j]);
      }
    }
    __builtin_amdgcn_s_setprio(0);
    cur ^= 1;
  }
#undef STAGE_W

  // epilogue: C[m][n] layout col=lane&31, row=(r&3)+8*(r>>2)+4h
#pragma unroll
  for (int j = 0; j < 3; ++j) {
    int ti = ng * 3 + j;          // 0..11, wave-uniform
    int gcol = ti * 32 + n32;
    if (ti < 4) {                 // q (scaled)
#pragma unroll
      for (int r = 0; r < 16; ++r) {
        int row = m0 + (r & 3) + 8 * (r >> 2) + 4 * h;
        qout[(size_t)row * 128 + gcol] = f2bf(acc[j][r] * QK_SCALE);
      }
    } else if (ti < 8) {          // k
#pragma unroll
      for (int r = 0; r < 16; ++r) {
        int row = m0 + (r & 3) + 8 * (r >> 2) + 4 * h;
        kout[(size_t)row * 128 + (gcol - 128)] = f2bf(acc[j][r]);
      }
    } else {                      // v -> v^T [B][128][T], 4 consecutive t
      int d = gcol - 256;
#pragma unroll
      for (int rq = 0; rq < 4; ++rq) {
        int t0 = m0 + rq * 8 + 4 * h;
        ushort4v o4;
#pragma unroll
        for (int i = 0; i < 4; ++i) o4[i] = f2bf(acc[j][rq * 4 + i]);
        *(ushort4v*)&vtout[(size_t)((t0 >> 12) * 128 + d) * 4096 + (t0 & 4095)] = o4;
      }
    }
  }
}

// ---------------- kernel 2: causal flash attention --------------------------
// 256 thr = 4 waves x 32 q-rows (128-row tile). NSPLIT KV split.
// Swapped QK^T: S^T[kv][q] = mfma(A=K, B=Q). Lane owns q-col = lane&31
// (pair with lane+32). K/V dbuf, 1 barrier/step, stage-after-barrier.
template <int NSPLIT>
__global__ __launch_bounds__(256, 2) void attn_kernel(const u16* __restrict__ qws,
                                                      const u16* __restrict__ kws,
                                                      const u16* __restrict__ vtws,
                                                      float* __restrict__ out,
                                                      float* __restrict__ opart,
                                                      float* __restrict__ mlpart) {
  __shared__ __align__(16) unsigned char Klds[2][16384];  // [64 kv][128 d] swz
  __shared__ __align__(16) unsigned char Vlds[2][16384];  // [128 d][64 kv] swz

  const int tid = threadIdx.x;
  const int w = tid >> 6;
  const int l = tid & 63;
  const int h = l >> 5, q32 = l & 31;
  const int bid = (int)blockIdx.x;
  const int sp = bid & (NSPLIT - 1);
  const int tb = bid / NSPLIT;
  const int bi = tb & 3;
  const int qt = 31 - (tb >> 2);   // reversed: long tiles first
  const int q0w = qt * 128 + w * 32;
  const int grow = bi * 4096 + q0w + q32;  // this lane's q row
  const int qg = q0w + q32;

  const int nsteps = 2 * qt + 2;
  const int s_lo = (nsteps * sp) / NSPLIT;
  const int s_hi = (nsteps * (sp + 1)) / NSPLIT;

  if constexpr (NSPLIT > 1) {
    if (s_lo >= s_hi) {
      if (h == 0) {
        mlpart[sp * 16384 + grow] = NEG_INF;
        mlpart[NSPLIT * 16384 + sp * 16384 + grow] = 0.f;
      }
      return;
    }
  }

  // Q B-frags resident: col=q32, k = ks*16 + 8h + e
  short8 qf[8];
  const u16* qp = qws + (size_t)grow * 128 + h * 8;
#pragma unroll
  for (int ks = 0; ks < 8; ++ks) qf[ks] = *(const short8*)(qp + ks * 16);

  f32x16 ot[4];
#pragma unroll
  for (int dt = 0; dt < 4; ++dt)
#pragma unroll
    for (int r = 0; r < 16; ++r) ot[dt][r] = 0.f;
  float mreg = NEG_INF, lsum = 0.f;

  const char* kbatch = (const char*)kws + (size_t)bi * 4096 * 256;
  const char* vbatch = (const char*)vtws + (size_t)bi * 128 * 8192;

  // staging: K tile 1024 chunks, V tile 1024 chunks; 4 each per thread
#define STAGE_KV(buf, kv0)                                                     \
  {                                                                            \
    _Pragma("unroll") for (int c = 0; c < 4; ++c) {                            \
      int L = c * 256 + tid;                                                   \
      int row = L >> 4, chp = L & 15;                                          \
      int gch = chp ^ (row & 7);                                               \
      gload16(kbatch + (size_t)((kv0) + row) * 256 + gch * 16,                 \
              (unsigned char*)Klds[buf] + c * 4096 + w * 1024);                \
    }                                                                          \
    _Pragma("unroll") for (int c = 0; c < 4; ++c) {                            \
      int L = c * 256 + tid;                                                   \
      int row = L >> 3, chp = L & 7;                                           \
      int gch = chp ^ (row & 7);                                               \
      gload16(vbatch + (size_t)row * 8192 + (size_t)(kv0) * 2 + gch * 16,      \
              (unsigned char*)Vlds[buf] + c * 4096 + w * 1024);                \
    }                                                                          \
  }

  STAGE_KV(0, s_lo * 64);
  int cur = 0;

  for (int s = s_lo; s < s_hi; ++s) {
    WAITVM0();                       // buf(cur) landed (own loads)
    __builtin_amdgcn_s_barrier();    // all waves drained + done with buf(cur^1)
    __builtin_amdgcn_sched_barrier(0);
    if (s + 1 < s_hi) STAGE_KV(cur ^ 1, (s + 1) * 64);
    const int kv0 = s * 64;
    const bool active = (kv0 <= q0w + 31);  // wave-uniform

    if (active) {
      // ---- S^T = K · Q^T : rows kv, cols q ----
      f32x16 st0, st1;
#pragma unroll
      for (int r = 0; r < 16; ++r) { st0[r] = 0.f; st1[r] = 0.f; }
      const char* Kb = (const char*)Klds[cur];
      const int sw = (q32 & 7) << 4;
      __builtin_amdgcn_s_setprio(1);
#pragma unroll
      for (int ks = 0; ks < 8; ++ks) {
        int coff = ks * 32 + h * 16;
        short8 a0 = *(const short8*)(Kb + q32 * 256 + (coff ^ sw));
        st0 = MFMA32(a0, qf[ks], st0);
        short8 a1 = *(const short8*)(Kb + (32 + q32) * 256 + (coff ^ sw));
        st1 = MFMA32(a1, qf[ks], st1);
      }
      __builtin_amdgcn_s_setprio(0);

      // ---- causal mask: kv > q -> -inf ----
      if (kv0 + 63 > q0w) {
#pragma unroll
        for (int r = 0; r < 16; ++r) {
          int kvr = kv0 + (r & 3) + 8 * (r >> 2) + 4 * h;
          if (kvr > qg) st0[r] = NEG_INF;
          if (kvr + 32 > qg) st1[r] = NEG_INF;
        }
      }

      // ---- online softmax (exp2 domain), defer-max THR=8 ----
      float tmax = st0[0];
#pragma unroll
      for (int r = 1; r < 16; ++r) tmax = fmaxf(tmax, st0[r]);
#pragma unroll
      for (int r = 0; r < 16; ++r) tmax = fmaxf(tmax, st1[r]);
      tmax = fmaxf(tmax, __shfl_xor(tmax, 32));
      if (!__all(tmax <= mreg + 8.0f)) {
        float mnew = fmaxf(mreg, tmax);
        float alpha = exp2f(mreg - mnew);
        lsum *= alpha;
#pragma unroll
        for (int dt = 0; dt < 4; ++dt)
#pragma unroll
          for (int r = 0; r < 16; ++r) ot[dt][r] *= alpha;
        mreg = mnew;
      }
      float rs = 0.f;
#pragma unroll
      for (int r = 0; r < 16; ++r) { st0[r] = exp2f(st0[r] - mreg); rs += st0[r]; }
#pragma unroll
      for (int r = 0; r < 16; ++r) { st1[r] = exp2f(st1[r] - mreg); rs += st1[r]; }
      rs += __shfl_xor(rs, 32);
      lsum += rs;

      // ---- O^T += V^T · P^T : per kv-16 tile build P B-frag in-register ----
      const char* Vb = (const char*)Vlds[cur];
      __builtin_amdgcn_s_setprio(1);
#pragma unroll
      for (int t = 0; t < 4; ++t) {
        const f32x16& stt = (t < 2) ? st0 : st1;
        const int rb = (t & 1) * 8;
        u32 A0 = cvtpk(stt[rb + 0], stt[rb + 1]);
        u32 C0 = cvtpk(stt[rb + 2], stt[rb + 3]);
        u32 B0 = cvtpk(stt[rb + 4], stt[rb + 5]);
        u32 D0 = cvtpk(stt[rb + 6], stt[rb + 7]);
        u32 Ax = (u32)__shfl_xor((int)A0, 32);
        u32 Bx = (u32)__shfl_xor((int)B0, 32);
        u32 Cx = (u32)__shfl_xor((int)C0, 32);
        u32 Dx = (u32)__shfl_xor((int)D0, 32);
        int4v pbv;
        pbv[0] = (int)(h ? Bx : A0);  // w0: e0,e1
        pbv[1] = (int)(h ? Dx : C0);  // w1: e2,e3
        pbv[2] = (int)(h ? B0 : Ax);  // w2: e4,e5
        pbv[3] = (int)(h ? D0 : Cx);  // w3: e6,e7
        short8 pb = __builtin_bit_cast(short8, pbv);
#pragma unroll
        for (int dt = 0; dt < 4; ++dt) {
          int row = dt * 32 + q32;
          short8 va = *(const short8*)(Vb + row * 128 + ((t * 32 + h * 16) ^ sw));
          ot[dt] = MFMA32(va, pb, ot[dt]);
        }
      }
      __builtin_amdgcn_s_setprio(0);
    }
    cur ^= 1;
  }

  // ---- epilogue: lane owns q-row `grow`, 64 d-values in f32x4 chunks ----
  if constexpr (NSPLIT == 1) {
    float inv = 1.0f / lsum;
    float* ob = out + (size_t)grow * 128;
#pragma unroll
    for (int dt = 0; dt < 4; ++dt)
#pragma unroll
      for (int rq = 0; rq < 4; ++rq) {
        f32x4 v4;
#pragma unroll
        for (int i = 0; i < 4; ++i) v4[i] = ot[dt][rq * 4 + i] * inv;
        *(f32x4*)(ob + dt * 32 + rq * 8 + 4 * h) = v4;
      }
  } else {
    float* ob = opart + ((size_t)sp * 16384 + grow) * 128;
#pragma unroll
    for (int dt = 0; dt < 4; ++dt)
#pragma unroll
      for (int rq = 0; rq < 4; ++rq) {
        f32x4 v4;
#pragma unroll
        for (int i = 0; i < 4; ++i) v4[i] = ot[dt][rq * 4 + i];
        *(f32x4*)(ob + dt * 32 + rq * 8 + 4 * h) = v4;
      }
    if (h == 0) {
      mlpart[sp * 16384 + grow] = mreg;
      mlpart[NSPLIT * 16384 + sp * 16384 + grow] = lsum;
    }
  }
#undef STAGE_KV
}

// ---------------- kernel 3: split combine -----------------------------------
__global__ __launch_bounds__(256) void combine_kernel(const float* __restrict__ opart,
                                                      const float* __restrict__ mlpart,
                                                      float* __restrict__ out) {
  int idx = blockIdx.x * 256 + threadIdx.x;  // 16384*128 threads
  int row = idx >> 7;
  float m0 = mlpart[row], m1 = mlpart[16384 + row];
  float m2 = mlpart[32768 + row], m3 = mlpart[49152 + row];
  float M = fmaxf(fmaxf(m0, m1), fmaxf(m2, m3));
  float s0 = exp2f(m0 - M), s1 = exp2f(m1 - M);
  float s2 = exp2f(m2 - M), s3 = exp2f(m3 - M);
  const float* lp = mlpart + 65536;
  float L = lp[row] * s0 + lp[16384 + row] * s1 + lp[32768 + row] * s2 + lp[49152 + row] * s3;
  size_t o = (size_t)idx;
  float O = opart[o] * s0 + opart[o + 2097152] * s1 +
            opart[o + 4194304] * s2 + opart[o + 6291456] * s3;
  out[o] = O / L;
}

// ---------------------------------------------------------------------------
extern "C" void kernel_launch(void* const* d_in, const int* in_sizes, int n_in,
                              void* d_out, int out_size, void* d_ws, size_t ws_size,
                              hipStream_t stream) {
  (void)in_sizes; (void)n_in; (void)out_size;
  const float* x  = (const float*)d_in[0];
  const float* Wq = (const float*)d_in[1];
  const float* Wk = (const float*)d_in[2];
  const float* Wv = (const float*)d_in[3];
  float* out = (float*)d_out;
  char* ws = (char*)d_ws;
  u16* qws  = (u16*)(ws);
  u16* kws  = (u16*)(ws + (4u << 20));
  u16* vtws = (u16*)(ws + (8u << 20));
  u16* Wb   = (u16*)(ws + (12u << 20));
  float* opart  = (float*)(ws + (13u << 20));   // 33.5 MiB
  float* mlpart = (float*)(ws + (47u << 20));   // 512 KiB

  wconv_kernel<<<dim3(192), dim3(256), 0, stream>>>(Wq, Wk, Wv, Wb);
  qkv_proj_kernel<<<dim3(256), dim3(512), 0, stream>>>(x, Wb, qws, kws, vtws);
  if (ws_size >= ((size_t)48 << 20)) {
    attn_kernel<4><<<dim3(512), dim3(256), 0, stream>>>(qws, kws, vtws, nullptr, opart, mlpart);
    combine_kernel<<<dim3(8192), dim3(256), 0, stream>>>(opart, mlpart, out);
  } else {
    attn_kernel<1><<<dim3(128), dim3(256), 0, stream>>>(qws, kws, vtws, out, nullptr, nullptr);
  }
}

// Round 5
// 91.686 us; speedup vs baseline: 2.0355x; 1.1929x over previous
//
#include <hip/hip_runtime.h>

// ---------------------------------------------------------------------------
// Attention fused for MI355X (gfx950)
//   x:[4,4096,1024] f32, Wq/Wk/Wv:[128,1024] f32 -> out:[4,4096,128] f32
// Round 5: qkv rewritten — x reg-staged (coalesced f32 -> cvt_pk -> ds_write,
//          XOR-swz, dbuf) + W gload16 dbuf; ONE __syncthreads per K-step with
//          post-barrier prefetch. attn/wconv/combine identical to round 4.
// ws: [0,4M) q bf16 (scaled by log2e/sqrt(128)), [4M,8M) k bf16,
//     [8M,12M) v^T bf16 [B][128][T], [12M,12.75M) W bf16,
//     [13M,46.5M) o partials f32 [4][16384][128], [47M,47.5M) m,l partials.
// ---------------------------------------------------------------------------

typedef __attribute__((ext_vector_type(8))) short short8;
typedef __attribute__((ext_vector_type(8))) unsigned short ushort8;
typedef __attribute__((ext_vector_type(4))) unsigned short ushort4v;
typedef __attribute__((ext_vector_type(4))) float f32x4;
typedef __attribute__((ext_vector_type(16))) float f32x16;
typedef __attribute__((ext_vector_type(4))) int int4v;
typedef unsigned int u32;
typedef unsigned short u16;

#define MFMA32(a, b, c) __builtin_amdgcn_mfma_f32_32x32x16_bf16((a), (b), (c), 0, 0, 0)
#define WAITVM0() asm volatile("s_waitcnt vmcnt(0)" ::: "memory")
#define NEG_INF (-1e30f)

__device__ __forceinline__ void gload16(const void* g, void* l) {
  __builtin_amdgcn_global_load_lds((const __attribute__((address_space(1))) u32*)g,
                                   (__attribute__((address_space(3))) u32*)l, 16, 0, 0);
}

__device__ __forceinline__ u16 f2bf(float f) {  // f32 -> bf16 bits, RNE
  u32 u = __builtin_bit_cast(u32, f);
  u = u + 0x7FFFu + ((u >> 16) & 1u);
  return (u16)(u >> 16);
}

__device__ __forceinline__ u32 cvtpk(float lo, float hi) {  // {bf16(lo),bf16(hi)}
  u32 r;
  asm("v_cvt_pk_bf16_f32 %0, %1, %2" : "=v"(r) : "v"(lo), "v"(hi));
  return r;
}

// ---------------- kernel 0: W f32 -> bf16 (Wb[384][1024]) -------------------
__global__ __launch_bounds__(256) void wconv_kernel(const float* __restrict__ Wq,
                                                    const float* __restrict__ Wk,
                                                    const float* __restrict__ Wv,
                                                    u16* __restrict__ Wb) {
  int g = (blockIdx.x * 256 + threadIdx.x) * 8;
  const float* src;
  if (g < 131072)      src = Wq + g;
  else if (g < 262144) src = Wk + (g - 131072);
  else                 src = Wv + (g - 262144);
  float4 a = *(const float4*)src;
  float4 b = *(const float4*)(src + 4);
  ushort8 o;
  o[0] = f2bf(a.x); o[1] = f2bf(a.y); o[2] = f2bf(a.z); o[3] = f2bf(a.w);
  o[4] = f2bf(b.x); o[5] = f2bf(b.y); o[6] = f2bf(b.z); o[7] = f2bf(b.w);
  *(ushort8*)(Wb + g) = o;
}

// ---------------- kernel 1: fused QKV projection ----------------------------
// grid 256 (BM=64), 512 thr = 8 waves: mh = w>>2 (32-row half), ng = w&3.
// Per K-step(64): W [384][64]bf16 dbuf via gload16; x [64][64] reg-staged
// (coalesced f32x8 -> cvt_pk -> ds_write_b128, XOR swz) dbuf. 1 barrier/step.
#define QK_SCALE 0.127517446f  // (1/sqrt(128)) * log2(e)

__global__ __launch_bounds__(512, 2) void qkv_proj_kernel(const float* __restrict__ x,
                                                          const u16* __restrict__ Wb,
                                                          u16* __restrict__ qout,
                                                          u16* __restrict__ kout,
                                                          u16* __restrict__ vtout) {
  __shared__ __align__(16) unsigned char Wlds[2][49152];  // [384][64] bf16 swz
  __shared__ __align__(16) unsigned char Xlds[2][8192];   // [64][64] bf16 swz
  const int tid = threadIdx.x;
  const int w = tid >> 6;
  const int l = tid & 63;
  const int h = l >> 5, n32 = l & 31;
  const int mh = w >> 2, ng = w & 3;
  const int m0 = (int)blockIdx.x * 64;

  // x staging role: row xr (0..63), col-group xc (8 f32 each) -> coalesced
  const int xr = tid >> 3, xc = tid & 7;
  const float* xsrc = x + (size_t)(m0 + xr) * 1024 + xc * 8;
  unsigned char* const xw0 = (unsigned char*)Xlds[0] + xr * 128 + ((xc * 16) ^ ((xr & 7) << 4));
  unsigned char* const xw1 = (unsigned char*)Xlds[1] + xr * 128 + ((xc * 16) ^ ((xr & 7) << 4));

  f32x16 acc[3];
#pragma unroll
  for (int j = 0; j < 3; ++j)
#pragma unroll
    for (int r = 0; r < 16; ++r) acc[j][r] = 0.f;

  // stage W k-slice ks (384 rows x 128B): 3072 chunks / 512 thr = 6 each
#define STAGE_W(buf, ks)                                                       \
  {                                                                            \
    _Pragma("unroll") for (int c = 0; c < 6; ++c) {                            \
      int L = c * 512 + tid;                                                   \
      int row = L >> 3, chp = L & 7;                                           \
      int gch = chp ^ (row & 7);                                               \
      gload16((const char*)Wb + row * 2048 + (ks) * 128 + gch * 16,            \
              (unsigned char*)Wlds[buf] + c * 8192 + w * 1024);                \
    }                                                                          \
  }

  // prologue: x(0) regs + W(0) in flight
  float4 xa = *(const float4*)(xsrc);
  float4 xb = *(const float4*)(xsrc + 4);
  STAGE_W(0, 0);

  const int am = mh * 32 + n32;        // this lane's A row within the 64-tile
  const int asw = (am & 7) << 4;
  int cur = 0;

  for (int ks = 0; ks < 16; ++ks) {
    // convert x(ks) regs -> Xlds[cur] (compiler waits the loads before cvt)
    int4v xv;
    xv[0] = (int)cvtpk(xa.x, xa.y);
    xv[1] = (int)cvtpk(xa.z, xa.w);
    xv[2] = (int)cvtpk(xb.x, xb.y);
    xv[3] = (int)cvtpk(xb.z, xb.w);
    *(int4v*)(cur ? xw1 : xw0) = xv;
    __syncthreads();  // vmcnt(0): W(ks) landed; lgkmcnt(0): ds_write retired
    if (ks < 15) {    // prefetch x(ks+1) + W(ks+1) -> lands during compute
      xa = *(const float4*)(xsrc + (ks + 1) * 64);
      xb = *(const float4*)(xsrc + (ks + 1) * 64 + 4);
      STAGE_W(cur ^ 1, ks + 1);
    }
    const char* xb0 = (const char*)Xlds[cur];
    const char* wb0 = (const char*)Wlds[cur];
    __builtin_amdgcn_s_setprio(1);
#pragma unroll
    for (int k16 = 0; k16 < 4; ++k16) {
      short8 a = *(const short8*)(xb0 + am * 128 + ((k16 * 32 + h * 16) ^ asw));
#pragma unroll
      for (int j = 0; j < 3; ++j) {
        int nrow = (ng * 3 + j) * 32 + n32;
        short8 b = *(const short8*)(wb0 + nrow * 128 +
                                    ((k16 * 32 + h * 16) ^ ((nrow & 7) << 4)));
        acc[j] = MFMA32(a, b, acc[j]);
      }
    }
    __builtin_amdgcn_s_setprio(0);
    cur ^= 1;
  }
#undef STAGE_W

  // epilogue: C[m][n] layout col=lane&31, row=(r&3)+8*(r>>2)+4h
  const int m0e = m0 + mh * 32;
#pragma unroll
  for (int j = 0; j < 3; ++j) {
    int ti = ng * 3 + j;          // 0..11, wave-uniform
    int gcol = ti * 32 + n32;
    if (ti < 4) {                 // q (scaled)
#pragma unroll
      for (int r = 0; r < 16; ++r) {
        int row = m0e + (r & 3) + 8 * (r >> 2) + 4 * h;
        qout[(size_t)row * 128 + gcol] = f2bf(acc[j][r] * QK_SCALE);
      }
    } else if (ti < 8) {          // k
#pragma unroll
      for (int r = 0; r < 16; ++r) {
        int row = m0e + (r & 3) + 8 * (r >> 2) + 4 * h;
        kout[(size_t)row * 128 + (gcol - 128)] = f2bf(acc[j][r]);
      }
    } else {                      // v -> v^T [B][128][T], 4 consecutive t
      int d = gcol - 256;
#pragma unroll
      for (int rq = 0; rq < 4; ++rq) {
        int t0 = m0e + rq * 8 + 4 * h;
        ushort4v o4;
#pragma unroll
        for (int i = 0; i < 4; ++i) o4[i] = f2bf(acc[j][rq * 4 + i]);
        *(ushort4v*)&vtout[(size_t)((t0 >> 12) * 128 + d) * 4096 + (t0 & 4095)] = o4;
      }
    }
  }
}

// ---------------- kernel 2: causal flash attention --------------------------
// 256 thr = 4 waves x 32 q-rows (128-row tile). NSPLIT KV split.
// Swapped QK^T: S^T[kv][q] = mfma(A=K, B=Q). Lane owns q-col = lane&31
// (pair with lane+32). K/V dbuf, 1 barrier/step, stage-after-barrier.
template <int NSPLIT>
__global__ __launch_bounds__(256, 2) void attn_kernel(const u16* __restrict__ qws,
                                                      const u16* __restrict__ kws,
                                                      const u16* __restrict__ vtws,
                                                      float* __restrict__ out,
                                                      float* __restrict__ opart,
                                                      float* __restrict__ mlpart) {
  __shared__ __align__(16) unsigned char Klds[2][16384];  // [64 kv][128 d] swz
  __shared__ __align__(16) unsigned char Vlds[2][16384];  // [128 d][64 kv] swz

  const int tid = threadIdx.x;
  const int w = tid >> 6;
  const int l = tid & 63;
  const int h = l >> 5, q32 = l & 31;
  const int bid = (int)blockIdx.x;
  const int sp = bid & (NSPLIT - 1);
  const int tb = bid / NSPLIT;
  const int bi = tb & 3;
  const int qt = 31 - (tb >> 2);   // reversed: long tiles first
  const int q0w = qt * 128 + w * 32;
  const int grow = bi * 4096 + q0w + q32;  // this lane's q row
  const int qg = q0w + q32;

  const int nsteps = 2 * qt + 2;
  const int s_lo = (nsteps * sp) / NSPLIT;
  const int s_hi = (nsteps * (sp + 1)) / NSPLIT;

  if constexpr (NSPLIT > 1) {
    if (s_lo >= s_hi) {
      if (h == 0) {
        mlpart[sp * 16384 + grow] = NEG_INF;
        mlpart[NSPLIT * 16384 + sp * 16384 + grow] = 0.f;
      }
      return;
    }
  }

  // Q B-frags resident: col=q32, k = ks*16 + 8h + e
  short8 qf[8];
  const u16* qp = qws + (size_t)grow * 128 + h * 8;
#pragma unroll
  for (int ks = 0; ks < 8; ++ks) qf[ks] = *(const short8*)(qp + ks * 16);

  f32x16 ot[4];
#pragma unroll
  for (int dt = 0; dt < 4; ++dt)
#pragma unroll
    for (int r = 0; r < 16; ++r) ot[dt][r] = 0.f;
  float mreg = NEG_INF, lsum = 0.f;

  const char* kbatch = (const char*)kws + (size_t)bi * 4096 * 256;
  const char* vbatch = (const char*)vtws + (size_t)bi * 128 * 8192;

  // staging: K tile 1024 chunks, V tile 1024 chunks; 4 each per thread
#define STAGE_KV(buf, kv0)                                                     \
  {                                                                            \
    _Pragma("unroll") for (int c = 0; c < 4; ++c) {                            \
      int L = c * 256 + tid;                                                   \
      int row = L >> 4, chp = L & 15;                                          \
      int gch = chp ^ (row & 7);                                               \
      gload16(kbatch + (size_t)((kv0) + row) * 256 + gch * 16,                 \
              (unsigned char*)Klds[buf] + c * 4096 + w * 1024);                \
    }                                                                          \
    _Pragma("unroll") for (int c = 0; c < 4; ++c) {                            \
      int L = c * 256 + tid;                                                   \
      int row = L >> 3, chp = L & 7;                                           \
      int gch = chp ^ (row & 7);                                               \
      gload16(vbatch + (size_t)row * 8192 + (size_t)(kv0) * 2 + gch * 16,      \
              (unsigned char*)Vlds[buf] + c * 4096 + w * 1024);                \
    }                                                                          \
  }

  STAGE_KV(0, s_lo * 64);
  int cur = 0;

  for (int s = s_lo; s < s_hi; ++s) {
    WAITVM0();                       // buf(cur) landed (own loads)
    __builtin_amdgcn_s_barrier();    // all waves drained + done with buf(cur^1)
    __builtin_amdgcn_sched_barrier(0);
    if (s + 1 < s_hi) STAGE_KV(cur ^ 1, (s + 1) * 64);
    const int kv0 = s * 64;
    const bool active = (kv0 <= q0w + 31);  // wave-uniform

    if (active) {
      // ---- S^T = K · Q^T : rows kv, cols q ----
      f32x16 st0, st1;
#pragma unroll
      for (int r = 0; r < 16; ++r) { st0[r] = 0.f; st1[r] = 0.f; }
      const char* Kb = (const char*)Klds[cur];
      const int sw = (q32 & 7) << 4;
      __builtin_amdgcn_s_setprio(1);
#pragma unroll
      for (int ks = 0; ks < 8; ++ks) {
        int coff = ks * 32 + h * 16;
        short8 a0 = *(const short8*)(Kb + q32 * 256 + (coff ^ sw));
        st0 = MFMA32(a0, qf[ks], st0);
        short8 a1 = *(const short8*)(Kb + (32 + q32) * 256 + (coff ^ sw));
        st1 = MFMA32(a1, qf[ks], st1);
      }
      __builtin_amdgcn_s_setprio(0);

      // ---- causal mask: kv > q -> -inf ----
      if (kv0 + 63 > q0w) {
#pragma unroll
        for (int r = 0; r < 16; ++r) {
          int kvr = kv0 + (r & 3) + 8 * (r >> 2) + 4 * h;
          if (kvr > qg) st0[r] = NEG_INF;
          if (kvr + 32 > qg) st1[r] = NEG_INF;
        }
      }

      // ---- online softmax (exp2 domain), defer-max THR=8 ----
      float tmax = st0[0];
#pragma unroll
      for (int r = 1; r < 16; ++r) tmax = fmaxf(tmax, st0[r]);
#pragma unroll
      for (int r = 0; r < 16; ++r) tmax = fmaxf(tmax, st1[r]);
      tmax = fmaxf(tmax, __shfl_xor(tmax, 32));
      if (!__all(tmax <= mreg + 8.0f)) {
        float mnew = fmaxf(mreg, tmax);
        float alpha = exp2f(mreg - mnew);
        lsum *= alpha;
#pragma unroll
        for (int dt = 0; dt < 4; ++dt)
#pragma unroll
          for (int r = 0; r < 16; ++r) ot[dt][r] *= alpha;
        mreg = mnew;
      }
      float rs = 0.f;
#pragma unroll
      for (int r = 0; r < 16; ++r) { st0[r] = exp2f(st0[r] - mreg); rs += st0[r]; }
#pragma unroll
      for (int r = 0; r < 16; ++r) { st1[r] = exp2f(st1[r] - mreg); rs += st1[r]; }
      rs += __shfl_xor(rs, 32);
      lsum += rs;

      // ---- O^T += V^T · P^T : per kv-16 tile build P B-frag in-register ----
      const char* Vb = (const char*)Vlds[cur];
      __builtin_amdgcn_s_setprio(1);
#pragma unroll
      for (int t = 0; t < 4; ++t) {
        const f32x16& stt = (t < 2) ? st0 : st1;
        const int rb = (t & 1) * 8;
        u32 A0 = cvtpk(stt[rb + 0], stt[rb + 1]);
        u32 C0 = cvtpk(stt[rb + 2], stt[rb + 3]);
        u32 B0 = cvtpk(stt[rb + 4], stt[rb + 5]);
        u32 D0 = cvtpk(stt[rb + 6], stt[rb + 7]);
        u32 Ax = (u32)__shfl_xor((int)A0, 32);
        u32 Bx = (u32)__shfl_xor((int)B0, 32);
        u32 Cx = (u32)__shfl_xor((int)C0, 32);
        u32 Dx = (u32)__shfl_xor((int)D0, 32);
        int4v pbv;
        pbv[0] = (int)(h ? Bx : A0);  // w0: e0,e1
        pbv[1] = (int)(h ? Dx : C0);  // w1: e2,e3
        pbv[2] = (int)(h ? B0 : Ax);  // w2: e4,e5
        pbv[3] = (int)(h ? D0 : Cx);  // w3: e6,e7
        short8 pb = __builtin_bit_cast(short8, pbv);
#pragma unroll
        for (int dt = 0; dt < 4; ++dt) {
          int row = dt * 32 + q32;
          short8 va = *(const short8*)(Vb + row * 128 + ((t * 32 + h * 16) ^ sw));
          ot[dt] = MFMA32(va, pb, ot[dt]);
        }
      }
      __builtin_amdgcn_s_setprio(0);
    }
    cur ^= 1;
  }

  // ---- epilogue: lane owns q-row `grow`, 64 d-values in f32x4 chunks ----
  if constexpr (NSPLIT == 1) {
    float inv = 1.0f / lsum;
    float* ob = out + (size_t)grow * 128;
#pragma unroll
    for (int dt = 0; dt < 4; ++dt)
#pragma unroll
      for (int rq = 0; rq < 4; ++rq) {
        f32x4 v4;
#pragma unroll
        for (int i = 0; i < 4; ++i) v4[i] = ot[dt][rq * 4 + i] * inv;
        *(f32x4*)(ob + dt * 32 + rq * 8 + 4 * h) = v4;
      }
  } else {
    float* ob = opart + ((size_t)sp * 16384 + grow) * 128;
#pragma unroll
    for (int dt = 0; dt < 4; ++dt)
#pragma unroll
      for (int rq = 0; rq < 4; ++rq) {
        f32x4 v4;
#pragma unroll
        for (int i = 0; i < 4; ++i) v4[i] = ot[dt][rq * 4 + i];
        *(f32x4*)(ob + dt * 32 + rq * 8 + 4 * h) = v4;
      }
    if (h == 0) {
      mlpart[sp * 16384 + grow] = mreg;
      mlpart[NSPLIT * 16384 + sp * 16384 + grow] = lsum;
    }
  }
#undef STAGE_KV
}

// ---------------- kernel 3: split combine -----------------------------------
__global__ __launch_bounds__(256) void combine_kernel(const float* __restrict__ opart,
                                                      const float* __restrict__ mlpart,
                                                      float* __restrict__ out) {
  int idx = blockIdx.x * 256 + threadIdx.x;  // 16384*128 threads
  int row = idx >> 7;
  float m0 = mlpart[row], m1 = mlpart[16384 + row];
  float m2 = mlpart[32768 + row], m3 = mlpart[49152 + row];
  float M = fmaxf(fmaxf(m0, m1), fmaxf(m2, m3));
  float s0 = exp2f(m0 - M), s1 = exp2f(m1 - M);
  float s2 = exp2f(m2 - M), s3 = exp2f(m3 - M);
  const float* lp = mlpart + 65536;
  float L = lp[row] * s0 + lp[16384 + row] * s1 + lp[32768 + row] * s2 + lp[49152 + row] * s3;
  size_t o = (size_t)idx;
  float O = opart[o] * s0 + opart[o + 2097152] * s1 +
            opart[o + 4194304] * s2 + opart[o + 6291456] * s3;
  out[o] = O / L;
}

// ---------------------------------------------------------------------------
extern "C" void kernel_launch(void* const* d_in, const int* in_sizes, int n_in,
                              void* d_out, int out_size, void* d_ws, size_t ws_size,
                              hipStream_t stream) {
  (void)in_sizes; (void)n_in; (void)out_size;
  const float* x  = (const float*)d_in[0];
  const float* Wq = (const float*)d_in[1];
  const float* Wk = (const float*)d_in[2];
  const float* Wv = (const float*)d_in[3];
  float* out = (float*)d_out;
  char* ws = (char*)d_ws;
  u16* qws  = (u16*)(ws);
  u16* kws  = (u16*)(ws + (4u << 20));
  u16* vtws = (u16*)(ws + (8u << 20));
  u16* Wb   = (u16*)(ws + (12u << 20));
  float* opart  = (float*)(ws + (13u << 20));   // 33.5 MiB
  float* mlpart = (float*)(ws + (47u << 20));   // 512 KiB

  wconv_kernel<<<dim3(192), dim3(256), 0, stream>>>(Wq, Wk, Wv, Wb);
  qkv_proj_kernel<<<dim3(256), dim3(512), 0, stream>>>(x, Wb, qws, kws, vtws);
  if (ws_size >= ((size_t)48 << 20)) {
    attn_kernel<4><<<dim3(512), dim3(256), 0, stream>>>(qws, kws, vtws, nullptr, opart, mlpart);
    combine_kernel<<<dim3(8192), dim3(256), 0, stream>>>(opart, mlpart, out);
  } else {
    attn_kernel<1><<<dim3(128), dim3(256), 0, stream>>>(qws, kws, vtws, out, nullptr, nullptr);
  }
}